// Round 11
// baseline (29.047 us; speedup 1.0000x reference)
//
#include <hip/hip_runtime.h>

#define BATCH 4
#define NROWS 2048
#define IN_DIM 1024
#define OUT_DIM 512
#define DSPLIT 16
#define NCHUNK 256          // chunks total (64 per batch)
#define RPB 32              // rows per chunk

typedef float f4 __attribute__((ext_vector_type(4)));

// ---- K1: w2part[ds][col] = sum_{d in slice} fc_w[d][col] * a2[d] ------
__global__ void __launch_bounds__(256)
k1_w2part(const float* __restrict__ fc_w,
          const float* __restrict__ attn_w,
          float* __restrict__ w2part) {
    int ds = blockIdx.x >> 2, cg = blockIdx.x & 3;   // 64 blocks
    int col = (cg << 8) + threadIdx.x;
    int d0 = ds << 5;
    float acc = 0.f;
#pragma unroll 8
    for (int j = 0; j < 32; ++j)
        acc += fc_w[(size_t)(d0 + j) * IN_DIM + col] * attn_w[OUT_DIM + d0 + j];
    w2part[(ds << 10) + col] = acc;
}

// ---- K2: per-chunk flash pass: yu_c = sum_r e^{s2_r} x_r, Zc = sum e --
// 256 blocks x 512 threads; 8 waves x 4 rows; x read ONCE (nontemporal).
__global__ void __launch_bounds__(512)
k2_chunk(const float* __restrict__ x,
         const float* __restrict__ w2part,
         float* __restrict__ yu,
         float* __restrict__ Zc) {
    const int bid = blockIdx.x, t = threadIdx.x;
    const int w = t >> 6, lane = t & 63;
    __shared__ float w2s[IN_DIM];                 // 4 KB
    __shared__ f4 sbuf[8 * 256];                  // 32 KB
    __shared__ float zbuf[8];

    if (t < 256) {
        const f4* wp = (const f4*)w2part;
        f4 s = {0.f, 0.f, 0.f, 0.f};
#pragma unroll
        for (int ds = 0; ds < DSPLIT; ++ds) s += wp[(ds << 8) + t];
        ((f4*)w2s)[t] = s;
    }
    __syncthreads();

    const f4* x4 = (const f4*)x;
    const f4* w2s4 = (const f4*)w2s;
    const f4 u0 = w2s4[lane],       u1 = w2s4[lane + 64],
             u2 = w2s4[lane + 128], u3 = w2s4[lane + 192];

    size_t row0 = (size_t)bid * RPB + (w << 2);
    f4 a0 = {0,0,0,0}, a1 = {0,0,0,0}, a2 = {0,0,0,0}, a3 = {0,0,0,0};
    float zw = 0.f;
#pragma unroll
    for (int r = 0; r < 4; ++r) {
        size_t base = (row0 + r) << 8;            // f4 units
        f4 v0 = __builtin_nontemporal_load(&x4[base + lane]);
        f4 v1 = __builtin_nontemporal_load(&x4[base + lane + 64]);
        f4 v2 = __builtin_nontemporal_load(&x4[base + lane + 128]);
        f4 v3 = __builtin_nontemporal_load(&x4[base + lane + 192]);
        f4 p = v0 * u0 + v1 * u1 + v2 * u2 + v3 * u3;
        float d = (p.x + p.y) + (p.z + p.w);
#pragma unroll
        for (int off = 32; off; off >>= 1) d += __shfl_xor(d, off, 64);
        float e = __expf(d);            // |s2| <~ 3: safe fp32; softmax max-term cancels exactly
        zw += e;
        a0 += e * v0; a1 += e * v1; a2 += e * v2; a3 += e * v3;
    }
    sbuf[(w << 8) + lane]       = a0;
    sbuf[(w << 8) + lane + 64]  = a1;
    sbuf[(w << 8) + lane + 128] = a2;
    sbuf[(w << 8) + lane + 192] = a3;
    if (lane == 0) zbuf[w] = zw;
    __syncthreads();

    // publish yu with all 512 threads (float2 granularity); stores stay cached (k3 re-reads)
    {
        const float2* sb2 = (const float2*)sbuf;      // 8 x 512 float2
        float2 s = {0.f, 0.f};
#pragma unroll
        for (int i = 0; i < 8; ++i) {
            float2 q = sb2[(i << 9) + t];
            s.x += q.x; s.y += q.y;
        }
        ((float2*)(yu + ((size_t)bid << 10)))[t] = s;
    }
    if (t == 0) {
        float z = 0.f;
#pragma unroll
        for (int i = 0; i < 8; ++i) z += zbuf[i];
        Zc[bid] = z;
    }
}

// ---- K3: y merge (redundant) + c slice + out tile (fused epilogue) ----
// 128 blocks: (b, ds in [0,16), rg in [0,2)). Each block merges its
// batch's y (256 KB L2/L3 — same aggregate redundancy as the unfused k3),
// computes c[d] for d in [ds*32, ds*32+32), and writes out rows
// [rg*1024, +1024) x cols [ds*32, +32): per row 128 B contiguous and
// 128 B aligned (full cacheline), nontemporal.
__global__ void __launch_bounds__(256)
k3_fused(const float* __restrict__ yu,
         const float* __restrict__ Zc,
         const float* __restrict__ fc_w,
         const float* __restrict__ fc_b,
         f4* __restrict__ out) {
    const int bid = blockIdx.x;
    const int b = bid >> 5, rem = bid & 31, ds = rem >> 1, rg = rem & 1;
    const int t = threadIdx.x, w = t >> 6, lane = t & 63;
    __shared__ float ys[IN_DIM];
    __shared__ float cs[32];
    __shared__ float zsh;

    if (w == 0) {
        float z = Zc[(b << 6) + lane];
#pragma unroll
        for (int off = 32; off; off >>= 1) z += __shfl_xor(z, off, 64);
        if (lane == 0) zsh = 1.f / z;
    }

    // merge this batch's 64 chunk partials: thread t owns f4 col t
    const f4* yu4 = (const f4*)yu + ((size_t)b << 14);
    f4 acc = {0.f, 0.f, 0.f, 0.f};
#pragma unroll 8
    for (int c = 0; c < 64; ++c) acc += yu4[(c << 8) + t];
    __syncthreads();
    acc *= zsh;
    ((f4*)ys)[t] = acc;
    __syncthreads();

    // c-slice: wave w computes 8 d's
    const f4* ys4 = (const f4*)ys;
    const f4 y0 = ys4[lane],       y1 = ys4[lane + 64],
             y2 = ys4[lane + 128], y3 = ys4[lane + 192];
#pragma unroll
    for (int q = 0; q < 8; ++q) {
        int dl = (w << 3) + q;
        int d = (ds << 5) + dl;
        const f4* fr = (const f4*)fc_w + ((size_t)d << 8);
        f4 p = fr[lane] * y0 + fr[lane + 64] * y1 + fr[lane + 128] * y2 + fr[lane + 192] * y3;
        float s = (p.x + p.y) + (p.z + p.w);
#pragma unroll
        for (int off = 32; off; off >>= 1) s += __shfl_xor(s, off, 64);
        if (lane == 0) cs[dl] = s + fc_b[d];
    }
    __syncthreads();

    // out tile write: thread t -> local row lr = t>>3, f4-col = t&7
    const f4 val = ((const f4*)cs)[t & 7];
    const int lr = t >> 3;
    size_t base = ((size_t)b * NROWS + ((size_t)rg << 10) + lr) * 128 + (ds << 3) + (t & 7);
#pragma unroll
    for (int it = 0; it < 32; ++it)
        __builtin_nontemporal_store(val, out + base + (size_t)it * 32 * 128);
}

extern "C" void kernel_launch(void* const* d_in, const int* in_sizes, int n_in,
                              void* d_out, int out_size, void* d_ws, size_t ws_size,
                              hipStream_t stream) {
    const float* x      = (const float*)d_in[0];
    const float* fc_w   = (const float*)d_in[1];
    const float* fc_b   = (const float*)d_in[2];
    const float* attn_w = (const float*)d_in[3];
    // attn_b (d_in[4]) cancels in the softmax — unused.

    float* wsf    = (float*)d_ws;
    float* w2part = wsf;                               // 16384
    float* Zc     = w2part + DSPLIT * IN_DIM;          // 256
    float* yu     = Zc + NCHUNK;                       // 262144
    float* out    = (float*)d_out;                     // ws total ~1.07 MB

    k1_w2part<<<64,     256, 0, stream>>>(fc_w, attn_w, w2part);
    k2_chunk <<<NCHUNK, 512, 0, stream>>>(x, w2part, yu, Zc);
    k3_fused <<<128,    256, 0, stream>>>(yu, Zc, fc_w, fc_b, (f4*)out);
}